// Round 7
// baseline (350.371 us; speedup 1.0000x reference)
//
#include <hip/hip_runtime.h>
#include <hip/hip_cooperative_groups.h>

namespace cg = cooperative_groups;

#define NV 100000
#define NJ 24
#define NP 207
#define VPB 4                      // verts per tile
#define NTILES (NV / VPB)          // 25000
#define TF4 (VPB * 3 * NP / 4)     // 621 float4 per tile
#define TF4PAD 768                 // padded (clamped-stage dest overflow region)
#define GRID 1024                  // 4 blocks/CU * 256 CU, all co-resident
#define SHBLK 625                  // blocks doing shape+jreg
#define VSLICE 160                 // verts per shape block (625*160 = 100000)

// Stage one tile (621 float4) into LDS. 3 rounds, source CLAMPED (never
// masked) so every wave issues exactly 3 global_load_lds -> uniform vmcnt.
// Clamped lanes write into the pad region [621..768).
__device__ __forceinline__ void stage_tile(float4* dst, const float4* src, int tid) {
  #pragma unroll
  for (int r = 0; r < 3; ++r) {
    int i4 = r * 256 + tid;
    int i4c = (i4 < TF4) ? i4 : (TF4 - 1);
    __builtin_amdgcn_global_load_lds(
        (const __attribute__((address_space(1))) void*)(src + i4c),
        (__attribute__((address_space(3))) void*)(dst + r * 256 + (tid & 192)),
        16, 0, 0);
  }
}

__global__ __launch_bounds__(256, 4) void k_all(
    const float* __restrict__ betas, const float* __restrict__ pose,
    const float* __restrict__ scale_p, const float* __restrict__ trans_p,
    const float* __restrict__ v_template, const float* __restrict__ shapedirs,
    const float* __restrict__ posedirs, const float* __restrict__ Jreg,
    const float* __restrict__ weights, float* __restrict__ vbuf,
    float* __restrict__ ws) {
  __shared__ float4 tile[3][TF4PAD];   // 36864 B
  __shared__ float sb[10];
  float* jpart = ws;                   // [625][72]
  float* lrot  = ws + 45056;           // 207
  float* rel   = ws + 45312;           // 288

  int tid = threadIdx.x, b = blockIdx.x;
  int w = tid >> 6, lane = tid & 63;
  const float4* pd4 = (const float4*)posedirs;
  cg::grid_group grid = cg::this_grid();

  // ---- prologue: start posedirs prefetch immediately (tiles b, b+GRID) ----
  stage_tile(&tile[0][0], pd4 + (size_t)b * TF4, tid);
  stage_tile(&tile[1][0], pd4 + (size_t)(b + GRID) * TF4, tid);

  // ---- phase A: v_shaped + J partials (blocks 0..624) ----
  if (b < SHBLK) {
    if (tid < 10) sb[tid] = betas[tid];
    __syncthreads();
    int R0 = b * (VSLICE * 3);
    #pragma unroll
    for (int rr = 0; rr < 2; ++rr) {
      int r = rr * 256 + tid;
      if (r < VSLICE * 3) {
        int Rg = R0 + r;
        const float2* sd = (const float2*)(shapedirs + (size_t)Rg * 10);
        float a = v_template[Rg];
        #pragma unroll
        for (int s = 0; s < 5; ++s) {
          float2 x = sd[s];
          a += x.x * sb[2 * s] + x.y * sb[2 * s + 1];
        }
        vbuf[Rg] = a;
      }
    }
    __syncthreads();  // vbuf slice written & visible within CU (L1)
    int v0 = b * VSLICE;
    #pragma unroll
    for (int jj = 0; jj < 6; ++jj) {
      int j = 6 * w + jj;
      float s0 = 0.f, s1 = 0.f, s2 = 0.f;
      #pragma unroll
      for (int i = 0; i < 3; ++i) {
        int vo = lane + 64 * i;
        if (vo < VSLICE) {
          int v = v0 + vo;
          float wv = Jreg[(size_t)j * NV + v];
          s0 += wv * vbuf[3 * v + 0];
          s1 += wv * vbuf[3 * v + 1];
          s2 += wv * vbuf[3 * v + 2];
        }
      }
      #pragma unroll
      for (int off = 32; off > 0; off >>= 1) {
        s0 += __shfl_xor(s0, off);
        s1 += __shfl_xor(s1, off);
        s2 += __shfl_xor(s2, off);
      }
      if (lane == 0) {
        jpart[b * 72 + j * 3 + 0] = s0;
        jpart[b * 72 + j * 3 + 1] = s1;
        jpart[b * 72 + j * 3 + 2] = s2;
      }
    }
  }
  grid.sync();  // sync1: all jpart + vbuf(v_shaped) visible device-wide

  // ---- FK: block 0 only (scratch aliased into tile[2]) ----
  if (b == 0) {
    float* fk = (float*)&tile[2][0];
    float* J = fk;            // [24][3]
    float* R = fk + 72;       // [24][9]
    float* G = fk + 288;      // [24][12]
    if (tid < 72) {
      float acc = 0.f;
      for (int bb = 0; bb < SHBLK; ++bb) acc += jpart[bb * 72 + tid];
      J[tid] = acc;
    }
    __syncthreads();
    if (tid < NJ) {
      float rx = pose[tid * 3 + 0], ry = pose[tid * 3 + 1], rz = pose[tid * 3 + 2];
      float tx = rx + 1e-8f, ty = ry + 1e-8f, tz = rz + 1e-8f;
      float theta = sqrtf(tx * tx + ty * ty + tz * tz);
      float x = rx / theta, y = ry / theta, z = rz / theta;
      float c = cosf(theta), s = sinf(theta), C = 1.f - c;
      float* Rr = R + tid * 9;
      Rr[0] = c + C * x * x;     Rr[1] = C * x * y - s * z; Rr[2] = C * x * z + s * y;
      Rr[3] = C * x * y + s * z; Rr[4] = c + C * y * y;     Rr[5] = C * y * z - s * x;
      Rr[6] = C * x * z - s * y; Rr[7] = C * y * z + s * x; Rr[8] = c + C * z * z;
      if (tid >= 1) {
        #pragma unroll
        for (int e = 0; e < 9; ++e) {
          float id = (e == 0 || e == 4 || e == 8) ? 1.f : 0.f;
          lrot[(tid - 1) * 9 + e] = Rr[e] - id;
        }
      }
    }
    __syncthreads();
    if (tid == 0) {
      const int par[NJ] = {-1,0,0,0,1,2,3,4,5,6,7,8,9,9,9,12,13,14,16,17,18,19,20,21};
      for (int a = 0; a < 3; ++a) {
        for (int bb = 0; bb < 3; ++bb) G[a * 4 + bb] = R[a * 3 + bb];
        G[a * 4 + 3] = J[a];
      }
      for (int i = 1; i < NJ; ++i) {
        int p = par[i];
        float t0 = J[i * 3 + 0] - J[p * 3 + 0];
        float t1 = J[i * 3 + 1] - J[p * 3 + 1];
        float t2 = J[i * 3 + 2] - J[p * 3 + 2];
        for (int a = 0; a < 3; ++a) {
          float g0 = G[p * 12 + a * 4 + 0], g1 = G[p * 12 + a * 4 + 1], g2 = G[p * 12 + a * 4 + 2];
          for (int bb = 0; bb < 3; ++bb)
            G[i * 12 + a * 4 + bb] =
                g0 * R[i * 9 + 0 * 3 + bb] + g1 * R[i * 9 + 1 * 3 + bb] + g2 * R[i * 9 + 2 * 3 + bb];
          G[i * 12 + a * 4 + 3] = G[p * 12 + a * 4 + 3] + g0 * t0 + g1 * t1 + g2 * t2;
        }
      }
    }
    __syncthreads();
    if (tid < NJ) {
      for (int a = 0; a < 3; ++a) {
        float corr = G[tid * 12 + a * 4 + 0] * J[tid * 3 + 0] +
                     G[tid * 12 + a * 4 + 1] * J[tid * 3 + 1] +
                     G[tid * 12 + a * 4 + 2] * J[tid * 3 + 2];
        rel[tid * 12 + a * 4 + 0] = G[tid * 12 + a * 4 + 0];
        rel[tid * 12 + a * 4 + 1] = G[tid * 12 + a * 4 + 1];
        rel[tid * 12 + a * 4 + 2] = G[tid * 12 + a * 4 + 2];
        rel[tid * 12 + a * 4 + 3] = G[tid * 12 + a * 4 + 3] - corr;
      }
    }
  }
  grid.sync();  // sync2: lrot/rel visible device-wide

  // ---- per-lane constants for the main loop ----
  float llr[4];
  #pragma unroll
  for (int e = 0; e < 4; ++e) {
    int p = lane + 64 * e;
    llr[e] = (p < NP) ? lrot[p] : 0.f;
  }
  float rlq[12];
  #pragma unroll
  for (int e = 0; e < 12; ++e) rlq[e] = (lane < NJ) ? rel[lane * 12 + e] : 0.f;
  float sc = scale_p[0];
  float tr = (lane < 3) ? trans_p[lane] : 0.f;

  // clean vmcnt base: drain everything (prologue tiles landed long ago)
  asm volatile("s_waitcnt vmcnt(0)" ::: "memory");
  __syncthreads();

  // ---- main loop: pose-blend + LBS, depth-2 counted-vmcnt pipeline ----
  float4* bc = &tile[0][0];  // compute  (tile b + it*GRID)
  float4* bn = &tile[1][0];  // next     (tile b + (it+1)*GRID)
  float4* bs = &tile[2][0];  // stage    (tile b + (it+2)*GRID)
  int nt = (NTILES - 1 - b) / GRID + 1;
  for (int it = 0; it < nt; ++it) {
    int tst = b + (it + 2) * GRID;
    if (tst >= NTILES) tst = NTILES - 1;  // dummy: keeps per-wave counts uniform
    stage_tile(bs, pd4 + (size_t)tst * TF4, tid);
    asm volatile("s_waitcnt vmcnt(6)" ::: "memory");
    __builtin_amdgcn_sched_barrier(0);
    __builtin_amdgcn_s_barrier();
    __builtin_amdgcn_sched_barrier(0);

    int v = (b + it * GRID) * VPB + w;
    float pvl = (lane < 3) ? vbuf[(size_t)3 * v + lane] : 0.f;
    float wj = (lane < NJ) ? weights[(size_t)v * NJ + lane] : 0.f;
    const float* row = (const float*)bc + w * (3 * NP);
    float a0 = 0.f, a1 = 0.f, a2 = 0.f;
    #pragma unroll
    for (int e = 0; e < 4; ++e) {
      int p = lane + 64 * e;
      if (p < NP) {
        float l = llr[e];
        a0 += row[p] * l;
        a1 += row[NP + p] * l;
        a2 += row[2 * NP + p] * l;
      }
    }
    #pragma unroll
    for (int off = 32; off > 0; off >>= 1) {
      a0 += __shfl_xor(a0, off);
      a1 += __shfl_xor(a1, off);
      a2 += __shfl_xor(a2, off);
    }
    float p0 = __shfl(pvl, 0) + a0;
    float p1 = __shfl(pvl, 1) + a1;
    float p2 = __shfl(pvl, 2) + a2;
    float q0 = rlq[0] * p0 + rlq[1] * p1 + rlq[2]  * p2 + rlq[3];
    float q1 = rlq[4] * p0 + rlq[5] * p1 + rlq[6]  * p2 + rlq[7];
    float q2 = rlq[8] * p0 + rlq[9] * p1 + rlq[10] * p2 + rlq[11];
    float r0 = wj * q0, r1 = wj * q1, r2 = wj * q2;
    #pragma unroll
    for (int off = 32; off > 0; off >>= 1) {
      r0 += __shfl_xor(r0, off);
      r1 += __shfl_xor(r1, off);
      r2 += __shfl_xor(r2, off);
    }
    if (lane < 3) {
      float oo = (lane == 0) ? r0 : (lane == 1) ? r1 : r2;
      vbuf[(size_t)3 * v + lane] = oo * sc + tr;
    }
    __builtin_amdgcn_sched_barrier(0);
    __builtin_amdgcn_s_barrier();
    __builtin_amdgcn_sched_barrier(0);
    float4* tmp = bc; bc = bn; bn = bs; bs = tmp;
  }
  asm volatile("s_waitcnt vmcnt(0)" ::: "memory");  // drain dummy stages
}

extern "C" void kernel_launch(void* const* d_in, const int* in_sizes, int n_in,
                              void* d_out, int out_size, void* d_ws, size_t ws_size,
                              hipStream_t stream) {
  const float* betas      = (const float*)d_in[0];
  const float* pose       = (const float*)d_in[1];
  const float* scale      = (const float*)d_in[2];
  const float* trans      = (const float*)d_in[3];
  const float* v_template = (const float*)d_in[4];
  const float* shapedirs  = (const float*)d_in[5];
  const float* posedirs   = (const float*)d_in[6];
  const float* Jreg       = (const float*)d_in[7];
  const float* weights    = (const float*)d_in[8];
  float* out = (float*)d_out;
  float* ws  = (float*)d_ws;

  void* args[] = {(void*)&betas, (void*)&pose, (void*)&scale, (void*)&trans,
                  (void*)&v_template, (void*)&shapedirs, (void*)&posedirs,
                  (void*)&Jreg, (void*)&weights, (void*)&out, (void*)&ws};
  hipLaunchCooperativeKernel((void*)k_all, dim3(GRID), dim3(256), args, 0, stream);
}

// Round 8
// 73.302 us; speedup vs baseline: 4.7798x; 4.7798x over previous
//
#include <hip/hip_runtime.h>

#define NV 100000
#define NJ 24
#define NP 207
#define VPB 8
#define NTILES (NV / VPB)      // 12500
#define TF4 1242               // float4 per tile = VPB*621/4
#define GRIDF 1024
#define SJBLK 250
#define VSLICE 400             // verts per k_sj block

// ---------------------------------------------------------------------------
// K1: fused shape-blend + J-regressor partials.
// Block bb: 400-vertex slice. Phase 1: v_shaped -> vbuf + LDS. Phase 2:
// per-wave 6 joints, partials over the slice -> jpartT[j*256+bb] (transposed).
// ---------------------------------------------------------------------------
__global__ __launch_bounds__(256) void k_sj(
    const float* __restrict__ betas, const float* __restrict__ v_template,
    const float* __restrict__ shapedirs, const float* __restrict__ Jreg,
    float* __restrict__ vbuf, float* __restrict__ jpartT) {
  __shared__ float sb[10];
  __shared__ float vsh[VSLICE * 3];
  int tid = threadIdx.x, bb = blockIdx.x;
  int w = tid >> 6, lane = tid & 63;
  if (tid < 10) sb[tid] = betas[tid];
  __syncthreads();
  int R0 = bb * (VSLICE * 3);
  for (int r = tid; r < VSLICE * 3; r += 256) {
    int Rg = R0 + r;
    const float2* sd = (const float2*)(shapedirs + (size_t)Rg * 10);
    float a = v_template[Rg];
    #pragma unroll
    for (int s = 0; s < 5; ++s) {
      float2 x = sd[s];
      a += x.x * sb[2 * s] + x.y * sb[2 * s + 1];
    }
    vsh[r] = a;
    vbuf[Rg] = a;
  }
  __syncthreads();
  int v0 = bb * VSLICE;
  #pragma unroll
  for (int jj = 0; jj < 6; ++jj) {
    int j = 6 * w + jj;
    float s0 = 0.f, s1 = 0.f, s2 = 0.f;
    #pragma unroll
    for (int i = 0; i < 7; ++i) {
      int vo = lane + 64 * i;
      if (vo < VSLICE) {
        float wv = Jreg[(size_t)j * NV + v0 + vo];
        s0 += wv * vsh[3 * vo + 0];
        s1 += wv * vsh[3 * vo + 1];
        s2 += wv * vsh[3 * vo + 2];
      }
    }
    #pragma unroll
    for (int off = 32; off > 0; off >>= 1) {
      s0 += __shfl_xor(s0, off);
      s1 += __shfl_xor(s1, off);
      s2 += __shfl_xor(s2, off);
    }
    if (lane == 0) {
      jpartT[(j * 3 + 0) * 256 + bb] = s0;
      jpartT[(j * 3 + 1) * 256 + bb] = s1;
      jpartT[(j * 3 + 2) * 256 + bb] = s2;
    }
  }
}

// ---------------------------------------------------------------------------
// K2: single block: reduce jpartT (per-thread contiguous float4 stream),
// rodrigues, FK chain, rel matrices, lrotmin.
// ---------------------------------------------------------------------------
__global__ __launch_bounds__(128) void k_fk(
    const float* __restrict__ pose, const float* __restrict__ jpartT,
    float* __restrict__ lrot, float* __restrict__ rel) {
  __shared__ float J[NJ * 3];
  __shared__ float R[NJ][9];
  __shared__ float G[NJ][12];
  int tid = threadIdx.x;
  if (tid < NJ * 3) {
    const float4* p4 = (const float4*)(jpartT + tid * 256);
    float a = 0.f;
    #pragma unroll 8
    for (int i = 0; i < SJBLK / 4; ++i) {
      float4 x = p4[i];
      a += x.x + x.y + x.z + x.w;
    }
    #pragma unroll
    for (int i = (SJBLK / 4) * 4; i < SJBLK; ++i) a += jpartT[tid * 256 + i];
    J[tid] = a;
  }
  __syncthreads();
  if (tid < NJ) {
    float rx = pose[tid * 3 + 0], ry = pose[tid * 3 + 1], rz = pose[tid * 3 + 2];
    float tx = rx + 1e-8f, ty = ry + 1e-8f, tz = rz + 1e-8f;
    float theta = sqrtf(tx * tx + ty * ty + tz * tz);
    float x = rx / theta, y = ry / theta, z = rz / theta;
    float c = cosf(theta), s = sinf(theta), C = 1.f - c;
    float* Rr = R[tid];
    Rr[0] = c + C * x * x;     Rr[1] = C * x * y - s * z; Rr[2] = C * x * z + s * y;
    Rr[3] = C * x * y + s * z; Rr[4] = c + C * y * y;     Rr[5] = C * y * z - s * x;
    Rr[6] = C * x * z - s * y; Rr[7] = C * y * z + s * x; Rr[8] = c + C * z * z;
    if (tid >= 1) {
      #pragma unroll
      for (int e = 0; e < 9; ++e) {
        float id = (e == 0 || e == 4 || e == 8) ? 1.f : 0.f;
        lrot[(tid - 1) * 9 + e] = Rr[e] - id;
      }
    }
  }
  __syncthreads();
  if (tid == 0) {
    const int par[NJ] = {-1,0,0,0,1,2,3,4,5,6,7,8,9,9,9,12,13,14,16,17,18,19,20,21};
    for (int a = 0; a < 3; ++a) {
      for (int b = 0; b < 3; ++b) G[0][a * 4 + b] = R[0][a * 3 + b];
      G[0][a * 4 + 3] = J[a];
    }
    for (int i = 1; i < NJ; ++i) {
      int p = par[i];
      float t0 = J[i * 3 + 0] - J[p * 3 + 0];
      float t1 = J[i * 3 + 1] - J[p * 3 + 1];
      float t2 = J[i * 3 + 2] - J[p * 3 + 2];
      for (int a = 0; a < 3; ++a) {
        float g0 = G[p][a * 4 + 0], g1 = G[p][a * 4 + 1], g2 = G[p][a * 4 + 2];
        for (int b = 0; b < 3; ++b)
          G[i][a * 4 + b] = g0 * R[i][0 * 3 + b] + g1 * R[i][1 * 3 + b] + g2 * R[i][2 * 3 + b];
        G[i][a * 4 + 3] = G[p][a * 4 + 3] + g0 * t0 + g1 * t1 + g2 * t2;
      }
    }
  }
  __syncthreads();
  if (tid < NJ) {
    for (int a = 0; a < 3; ++a) {
      float corr = G[tid][a * 4 + 0] * J[tid * 3 + 0] +
                   G[tid][a * 4 + 1] * J[tid * 3 + 1] +
                   G[tid][a * 4 + 2] * J[tid * 3 + 2];
      rel[tid * 12 + a * 4 + 0] = G[tid][a * 4 + 0];
      rel[tid * 12 + a * 4 + 1] = G[tid][a * 4 + 1];
      rel[tid * 12 + a * 4 + 2] = G[tid][a * 4 + 2];
      rel[tid * 12 + a * 4 + 3] = G[tid][a * 4 + 3] - corr;
    }
  }
}

// ---------------------------------------------------------------------------
// Stage one 8-vertex posedirs tile (1242 float4) into LDS via DMA.
// All 4 waves issue exactly 5 global_load_lds -> uniform vmcnt accounting.
// ---------------------------------------------------------------------------
__device__ __forceinline__ void stage_tile(float4* dst, const float4* src, int tid) {
  #pragma unroll
  for (int r = 0; r < 5; ++r) {
    int i4 = r * 256 + tid;
    if (i4 < TF4) {
      __builtin_amdgcn_global_load_lds(
          (const __attribute__((address_space(1))) void*)(src + i4),
          (__attribute__((address_space(3))) void*)(dst + r * 256 + (tid & 192)),
          16, 0, 0);
    }
  }
}

// ---------------------------------------------------------------------------
// K3: fused pose-blend + LBS, contiguous tile span per block, depth-1
// counted-vmcnt pipeline. Wave = 2 vertices (32 lanes each).
// ALL per-iter VMEM loads (pvl, wj) issue BEFORE the 5 stage ops, so
// vmcnt(5) covers them and the compute phase needs no further VM waits.
// ---------------------------------------------------------------------------
__global__ __launch_bounds__(256, 4) void k_fused(
    const float* __restrict__ posedirs, const float* __restrict__ weights,
    const float* __restrict__ lrot, const float* __restrict__ rel,
    const float* __restrict__ scale, const float* __restrict__ trans,
    float* __restrict__ vbuf) {
  __shared__ float4 tile[2][TF4];
  int tid = threadIdx.x, b = blockIdx.x;
  int wid = tid >> 6, lane = tid & 63, half = lane >> 5, lj = lane & 31;

  // contiguous span: blocks 0..211 get 13 tiles, rest 12
  int s_b = b * 12 + (b < 212 ? b : 212);
  int nt = 12 + (b < 212 ? 1 : 0);

  const float4* pd4 = (const float4*)posedirs;
  stage_tile(&tile[0][0], pd4 + (size_t)s_b * TF4, tid);

  float llr[7];
  #pragma unroll
  for (int e = 0; e < 7; ++e) {
    int p = lj + 32 * e;
    llr[e] = (p < NP) ? lrot[p] : 0.f;
  }
  float rlq[12];
  #pragma unroll
  for (int e = 0; e < 12; ++e) rlq[e] = (lj < NJ) ? rel[lj * 12 + e] : 0.f;
  float sc = scale[0];
  float tr = (lj < 3) ? trans[lj] : 0.f;

  __syncthreads();  // drains prologue DMA + aligns waves

  for (int it = 0; it < nt; ++it) {
    int cur = it & 1;
    int vv = (s_b + it) * VPB + (wid << 1) + half;
    // per-iter scalar loads FIRST (older than the 5 stage ops below)
    float pvl = (lj < 3) ? vbuf[(size_t)3 * vv + lj] : 0.f;
    float wj = (lj < NJ) ? weights[(size_t)vv * NJ + lj] : 0.f;
    int tnext = s_b + it + 1;
    if (tnext >= NTILES) tnext = NTILES - 1;  // dummy on last iter
    stage_tile(&tile[cur ^ 1][0], pd4 + (size_t)tnext * TF4, tid);
    asm volatile("s_waitcnt vmcnt(5)" ::: "memory");
    __builtin_amdgcn_sched_barrier(0);
    __builtin_amdgcn_s_barrier();
    __builtin_amdgcn_sched_barrier(0);

    const float* row = (const float*)&tile[cur][0] + ((wid << 1) + half) * (3 * NP);
    float a0 = 0.f, a1 = 0.f, a2 = 0.f;
    #pragma unroll
    for (int e = 0; e < 7; ++e) {
      int p = lj + 32 * e;
      if (p < NP) {
        float l = llr[e];
        a0 += row[p] * l;
        a1 += row[NP + p] * l;
        a2 += row[2 * NP + p] * l;
      }
    }
    #pragma unroll
    for (int off = 16; off > 0; off >>= 1) {
      a0 += __shfl_xor(a0, off);
      a1 += __shfl_xor(a1, off);
      a2 += __shfl_xor(a2, off);
    }
    int gb = lane & 32;
    float p0 = __shfl(pvl, gb + 0) + a0;
    float p1 = __shfl(pvl, gb + 1) + a1;
    float p2 = __shfl(pvl, gb + 2) + a2;
    float q0 = rlq[0] * p0 + rlq[1] * p1 + rlq[2]  * p2 + rlq[3];
    float q1 = rlq[4] * p0 + rlq[5] * p1 + rlq[6]  * p2 + rlq[7];
    float q2 = rlq[8] * p0 + rlq[9] * p1 + rlq[10] * p2 + rlq[11];
    float r0 = wj * q0, r1 = wj * q1, r2 = wj * q2;
    #pragma unroll
    for (int off = 16; off > 0; off >>= 1) {
      r0 += __shfl_xor(r0, off);
      r1 += __shfl_xor(r1, off);
      r2 += __shfl_xor(r2, off);
    }
    if (lj < 3) {
      float oo = (lj == 0) ? r0 : (lj == 1) ? r1 : r2;
      vbuf[(size_t)3 * vv + lj] = oo * sc + tr;
    }
    __builtin_amdgcn_sched_barrier(0);
    __builtin_amdgcn_s_barrier();
    __builtin_amdgcn_sched_barrier(0);
  }
  asm volatile("s_waitcnt vmcnt(0)" ::: "memory");  // drain dummy stage
}

extern "C" void kernel_launch(void* const* d_in, const int* in_sizes, int n_in,
                              void* d_out, int out_size, void* d_ws, size_t ws_size,
                              hipStream_t stream) {
  const float* betas      = (const float*)d_in[0];
  const float* pose       = (const float*)d_in[1];
  const float* scale      = (const float*)d_in[2];
  const float* trans      = (const float*)d_in[3];
  const float* v_template = (const float*)d_in[4];
  const float* shapedirs  = (const float*)d_in[5];
  const float* posedirs   = (const float*)d_in[6];
  const float* Jreg       = (const float*)d_in[7];
  const float* weights    = (const float*)d_in[8];
  float* out = (float*)d_out;
  float* ws  = (float*)d_ws;

  float* jpartT = ws;           // 72*256 = 18432 floats
  float* lrot   = ws + 18432;   // 207 floats
  float* rel    = ws + 18688;   // 288 floats

  k_sj<<<SJBLK, 256, 0, stream>>>(betas, v_template, shapedirs, Jreg, out, jpartT);
  k_fk<<<1, 128, 0, stream>>>(pose, jpartT, lrot, rel);
  k_fused<<<GRIDF, 256, 0, stream>>>(posedirs, weights, lrot, rel, scale, trans, out);
}